// Round 9
// baseline (56.687 us; speedup 1.0000x reference)
//
#include <hip/hip_runtime.h>
#include <hip/hip_bf16.h>

// B=128, C=32, K=128
// out[b,c,i,j] = s[b,c],  s[b,c] = sum_k (u[c,k]+b_row[c]) * (v[c,k]+b_col[c])
//   u[c,k] = sum_i w_row[c,i] * X[b,i,k]   (xs row-slice read)
//   v[c,k] = sum_j w_col[c,j] * X[b,k,j]   (xt row-slice read)
//
// compute_s v6: Nk=8 x Nc=4 register tile + 4-way i-split.
//  - lane = kq*4 + ih: kq picks 8-k slice, ih picks 32-i range
//  - per i-iter: 4 b128 (X) + 2 broadcast b128 (weights) -> 64 FMA
//    (2.7x fewer LDS instrs/FMA than R8's 4 instr/16 FMA)
//  - i-partials reduced in-register: shfl_xor 1,2 (ih); k via shfl_xor 4..32
//  - XCD-paired bid remap: both ch-blocks of a b land on one XCD -> L2 share
// Retained: plain stores (R3), two-kernel split (R6), no scalar weights (R7).

constexpr int KDIM = 128;
constexpr int CDIM = 32;
constexpr int LD   = 132;   // padded row stride (16B-aligned)

// grid = 256: xcd = bid&7, idx = bid>>3; b = xcd*16 + idx>>1, ch = idx&1
__global__ __launch_bounds__(256) void compute_s_kernel(
    const float* __restrict__ x,
    const float* __restrict__ w_col, const float* __restrict__ b_col,
    const float* __restrict__ w_row, const float* __restrict__ b_row,
    float* __restrict__ s_out)
{
    __shared__ float  xs[KDIM * LD];    // X row-major            (66 KB)
    __shared__ float  xt[KDIM * LD];    // X^T row-major          (66 KB)
    __shared__ float4 wu4[KDIM][4];     // wu4[i][g] = wr[C0+4g..+3][i]  (8 KB)
    __shared__ float4 wc4[KDIM][4];     // same for w_col                (8 KB)

    const int bid = blockIdx.x;
    const int xcd = bid & 7;
    const int idx = bid >> 3;              // 0..31
    const int b   = xcd * 16 + (idx >> 1); // paired ch-blocks share XCD
    const int ch  = idx & 1;
    const int C0  = ch * 16;
    const int tid = threadIdx.x;

    // ---- stage weight quads first (latency hides under X transpose) ----
    #pragma unroll
    for (int e = 0; e < 2; ++e) {
        const int ent = tid + 256 * e;     // 0..511
        const int i   = ent & 127;
        const int g   = ent >> 7;          // 0..3
        wu4[i][g] = make_float4(w_row[(C0 + 4 * g + 0) * KDIM + i],
                                w_row[(C0 + 4 * g + 1) * KDIM + i],
                                w_row[(C0 + 4 * g + 2) * KDIM + i],
                                w_row[(C0 + 4 * g + 3) * KDIM + i]);
        wc4[i][g] = make_float4(w_col[(C0 + 4 * g + 0) * KDIM + i],
                                w_col[(C0 + 4 * g + 1) * KDIM + i],
                                w_col[(C0 + 4 * g + 2) * KDIM + i],
                                w_col[(C0 + 4 * g + 3) * KDIM + i]);
    }

    // ---- merged X staging: 16 float4 loads feed BOTH xs and xt ----
    const float4* xsrc = reinterpret_cast<const float4*>(x + (size_t)b * KDIM * KDIM);
    const int tj  = tid & 31;    // column quad of X
    const int ti0 = tid >> 5;    // 0..7
    #pragma unroll
    for (int it = 0; it < 4; ++it) {
        const int ti = ti0 + 8 * it;                      // row quad, 0..31
        const float4 r0 = xsrc[(4 * ti + 0) * 32 + tj];   // coalesced
        const float4 r1 = xsrc[(4 * ti + 1) * 32 + tj];
        const float4 r2 = xsrc[(4 * ti + 2) * 32 + tj];
        const float4 r3 = xsrc[(4 * ti + 3) * 32 + tj];
        *reinterpret_cast<float4*>(&xs[(4 * ti + 0) * LD + 4 * tj]) = r0;
        *reinterpret_cast<float4*>(&xs[(4 * ti + 1) * LD + 4 * tj]) = r1;
        *reinterpret_cast<float4*>(&xs[(4 * ti + 2) * LD + 4 * tj]) = r2;
        *reinterpret_cast<float4*>(&xs[(4 * ti + 3) * LD + 4 * tj]) = r3;
        *reinterpret_cast<float4*>(&xt[(4 * tj + 0) * LD + 4 * ti]) =
            make_float4(r0.x, r1.x, r2.x, r3.x);
        *reinterpret_cast<float4*>(&xt[(4 * tj + 1) * LD + 4 * ti]) =
            make_float4(r0.y, r1.y, r2.y, r3.y);
        *reinterpret_cast<float4*>(&xt[(4 * tj + 2) * LD + 4 * ti]) =
            make_float4(r0.z, r1.z, r2.z, r3.z);
        *reinterpret_cast<float4*>(&xt[(4 * tj + 3) * LD + 4 * ti]) =
            make_float4(r0.w, r1.w, r2.w, r3.w);
    }
    __syncthreads();

    const int lane = tid & 63;
    const int wv   = tid >> 6;     // wave id 0..3 -> c-quad
    const int kq   = lane >> 2;    // 0..15 -> k0 = 8*kq
    const int ih   = lane & 3;     // i-range [32*ih, +32)
    const int k0   = kq * 8;

    float u[4][8] = {{0}}, v[4][8] = {{0}};

    #pragma unroll 2
    for (int ii = 0; ii < 32; ++ii) {
        const int i = ih * 32 + ii;
        const float4 xa = *reinterpret_cast<const float4*>(&xs[i * LD + k0]);
        const float4 xb = *reinterpret_cast<const float4*>(&xs[i * LD + k0 + 4]);
        const float4 ta = *reinterpret_cast<const float4*>(&xt[i * LD + k0]);
        const float4 tb = *reinterpret_cast<const float4*>(&xt[i * LD + k0 + 4]);
        const float4 wuq = wu4[i][wv];   // broadcast (same addr across wave)
        const float4 wcq = wc4[i][wv];
        const float xv[8] = {xa.x, xa.y, xa.z, xa.w, xb.x, xb.y, xb.z, xb.w};
        const float tv[8] = {ta.x, ta.y, ta.z, ta.w, tb.x, tb.y, tb.z, tb.w};
        const float wu_[4] = {wuq.x, wuq.y, wuq.z, wuq.w};
        const float wc_[4] = {wcq.x, wcq.y, wcq.z, wcq.w};
        #pragma unroll
        for (int cc = 0; cc < 4; ++cc) {
            #pragma unroll
            for (int kk = 0; kk < 8; ++kk) {
                u[cc][kk] = fmaf(wu_[cc], xv[kk], u[cc][kk]);
                v[cc][kk] = fmaf(wc_[cc], tv[kk], v[cc][kk]);
            }
        }
    }

    // ---- reduce i-partials across ih (lanes 0-3 of each quad) ----
    #pragma unroll
    for (int cc = 0; cc < 4; ++cc) {
        #pragma unroll
        for (int kk = 0; kk < 8; ++kk) {
            u[cc][kk] += __shfl_xor(u[cc][kk], 1);
            u[cc][kk] += __shfl_xor(u[cc][kk], 2);
            v[cc][kk] += __shfl_xor(v[cc][kk], 1);
            v[cc][kk] += __shfl_xor(v[cc][kk], 2);
        }
    }

    // ---- dot + bias, reduce over kq (lane bits 2..5) ----
    float p[4];
    #pragma unroll
    for (int cc = 0; cc < 4; ++cc) {
        const float br = b_row[C0 + 4 * wv + cc];
        const float bc = b_col[C0 + 4 * wv + cc];
        p[cc] = 0.f;
        #pragma unroll
        for (int kk = 0; kk < 8; ++kk)
            p[cc] += (u[cc][kk] + br) * (v[cc][kk] + bc);
        #pragma unroll
        for (int off = 4; off < 64; off <<= 1)
            p[cc] += __shfl_xor(p[cc], off);
    }
    if (lane == 0) {
        float* dst = s_out + b * CDIM + C0 + 4 * wv;
        dst[0] = p[0]; dst[1] = p[1]; dst[2] = p[2]; dst[3] = p[3];
    }
}

// grid = 2048 (two slabs per block), block = 256. Plain float4 stores.
__global__ __launch_bounds__(256) void bcast_kernel(
    const float* __restrict__ s, float* __restrict__ out)
{
    #pragma unroll
    for (int slab = 0; slab < 2; ++slab) {
        const int bc = blockIdx.x * 2 + slab;
        const float val = s[bc];
        float4 v4;
        v4.x = v4.y = v4.z = v4.w = val;
        float4* o = reinterpret_cast<float4*>(out) + (size_t)bc * 4096;
        #pragma unroll
        for (int r = 0; r < 16; ++r) {
            o[threadIdx.x + 256 * r] = v4;
        }
    }
}

extern "C" void kernel_launch(void* const* d_in, const int* in_sizes, int n_in,
                              void* d_out, int out_size, void* d_ws, size_t ws_size,
                              hipStream_t stream) {
    const float* x     = (const float*)d_in[0];
    const float* w_col = (const float*)d_in[1];
    const float* b_col = (const float*)d_in[2];
    const float* w_row = (const float*)d_in[3];
    const float* b_row = (const float*)d_in[4];
    float* out  = (float*)d_out;
    float* s_ws = (float*)d_ws;   // 4096 floats of scratch

    compute_s_kernel<<<256, 256, 0, stream>>>(x, w_col, b_col, w_row, b_row, s_ws);
    bcast_kernel<<<2048, 256, 0, stream>>>(s_ws, out);
}

// Round 10
// 52.203 us; speedup vs baseline: 1.0859x; 1.0859x over previous
//
#include <hip/hip_runtime.h>
#include <hip/hip_bf16.h>

// B=128, C=32, K=128
// out[b,c,i,j] = s[b,c],  s[b,c] = sum_k (u[c,k]+b_row[c]) * (v[c,k]+b_col[c])
//   u[c,k] = sum_i w_row[c,i] * X[b,i,k]   (xs row-slice read)
//   v[c,k] = sum_j w_col[c,j] * X[b,k,j]   (xt row-slice read)
//
// FUSED v2 (non-redundant, unlike R6): grid 256 = (b,ch), block 512.
// Each block computes its own 16 s values ONCE (R8 compute structure),
// then streams its own 16 slabs (1 MB). Removes: 2nd launch, kernel-boundary
// barrier (per-block tail smoothing), s HBM round-trip.
//  - xs linear LD=132 (stage + row-read conflict-free)
//  - xt via verified R5 XOR chunk swizzle (R8/R9 unswizzled staging was a
//    16-way write conflict: (4tj+t)*132+4ti = 16tj+... mod 32)
//  - weights as float2 pairs in LDS (R7: scalar s_load weights regressed,
//    SMEM+DS share lgkmcnt); 2-addr b64 broadcast is free
//  - 2-way i-split only (16 shfls; R9's 128 shfls ran on the LDS pipe)
// Plain stores (R3: nt regressed).

constexpr int KDIM = 128;
constexpr int CDIM = 32;
constexpr int LD   = 132;   // padded row stride for xs

// XOR chunk swizzle, linear [128][128] tile: conflict-free for 4x4-transpose
// b128 staging writes AND row-wise b128 reads (verified R4/R5).
__device__ __forceinline__ int swz_word(int row, int col) {
    return (row << 7) | ((((col >> 2) ^ ((row >> 2) & 7)) << 2) | (col & 3));
}

// grid = 256: xcd = bid&7, idx = bid>>3; b = xcd*16 + (idx>>1), ch = idx&1
// (both ch-blocks of a b share an XCD -> X_b L2-shared, HBM read ~8.4 MB)
__global__ __launch_bounds__(512) void fused_kernel(
    const float* __restrict__ x,
    const float* __restrict__ w_col, const float* __restrict__ b_col,
    const float* __restrict__ w_row, const float* __restrict__ b_row,
    float* __restrict__ out)
{
    __shared__ float  xs[KDIM * LD];    // X row-major, padded   (66 KB)
    __shared__ float  xt[KDIM * KDIM];  // X^T, chunk-swizzled   (64 KB)
    __shared__ float2 wpr[KDIM][8];     // (w_row[C0+g][i], w_row[C0+g+8][i]) (8 KB)
    __shared__ float2 wpc[KDIM][8];     // same for w_col                     (8 KB)
    __shared__ float  s_lds[16];

    const int bid = blockIdx.x;
    const int xcd = bid & 7;
    const int idx = bid >> 3;              // 0..31
    const int b   = xcd * 16 + (idx >> 1);
    const int ch  = idx & 1;
    const int C0  = ch * 16;
    const int tid = threadIdx.x;

    // ---- stage weight pairs first (latency hides under X transpose) ----
    #pragma unroll
    for (int e = 0; e < 2; ++e) {
        const int ent = tid + 512 * e;     // 0..1023
        const int i   = ent & 127;
        const int g   = ent >> 7;          // 0..7
        wpr[i][g] = make_float2(w_row[(C0 + g) * KDIM + i],
                                w_row[(C0 + g + 8) * KDIM + i]);
        wpc[i][g] = make_float2(w_col[(C0 + g) * KDIM + i],
                                w_col[(C0 + g + 8) * KDIM + i]);
    }

    // ---- merged X staging: 8 float4 loads/thread feed BOTH xs and xt ----
    const float4* xsrc = reinterpret_cast<const float4*>(x + (size_t)b * KDIM * KDIM);
    const int tj  = tid & 31;    // column quad of X
    const int ti0 = tid >> 5;    // 0..15
    #pragma unroll
    for (int it = 0; it < 2; ++it) {
        const int ti = ti0 + 16 * it;                     // row quad, 0..31
        const float4 r0 = xsrc[(4 * ti + 0) * 32 + tj];   // coalesced
        const float4 r1 = xsrc[(4 * ti + 1) * 32 + tj];
        const float4 r2 = xsrc[(4 * ti + 2) * 32 + tj];
        const float4 r3 = xsrc[(4 * ti + 3) * 32 + tj];
        *reinterpret_cast<float4*>(&xs[(4 * ti + 0) * LD + 4 * tj]) = r0;
        *reinterpret_cast<float4*>(&xs[(4 * ti + 1) * LD + 4 * tj]) = r1;
        *reinterpret_cast<float4*>(&xs[(4 * ti + 2) * LD + 4 * tj]) = r2;
        *reinterpret_cast<float4*>(&xs[(4 * ti + 3) * LD + 4 * tj]) = r3;
        *reinterpret_cast<float4*>(&xt[swz_word(4 * tj + 0, 4 * ti)]) =
            make_float4(r0.x, r1.x, r2.x, r3.x);
        *reinterpret_cast<float4*>(&xt[swz_word(4 * tj + 1, 4 * ti)]) =
            make_float4(r0.y, r1.y, r2.y, r3.y);
        *reinterpret_cast<float4*>(&xt[swz_word(4 * tj + 2, 4 * ti)]) =
            make_float4(r0.z, r1.z, r2.z, r3.z);
        *reinterpret_cast<float4*>(&xt[swz_word(4 * tj + 3, 4 * ti)]) =
            make_float4(r0.w, r1.w, r2.w, r3.w);
    }
    __syncthreads();

    // ---- compute: wave w owns c-pair {C0+w, C0+w+8}; lane = ih*32 + kq ----
    const int w    = tid >> 6;     // wave id 0..7
    const int lane = tid & 63;
    const int kq   = lane & 31;    // 4-k chunk -> k0
    const int ih   = lane >> 5;    // i-half
    const int k0   = 4 * kq;

    float au0[4] = {0,0,0,0}, au1[4] = {0,0,0,0};
    float av0[4] = {0,0,0,0}, av1[4] = {0,0,0,0};

    #pragma unroll 4
    for (int ii = 0; ii < 64; ++ii) {
        const int i = ih * 64 + ii;
        const float4 xv = *reinterpret_cast<const float4*>(&xs[i * LD + k0]);
        const float4 tv = *reinterpret_cast<const float4*>(&xt[swz_word(i, k0)]);
        const float2 wu = wpr[i][w];
        const float2 wv = wpc[i][w];
        au0[0] = fmaf(wu.x, xv.x, au0[0]); au0[1] = fmaf(wu.x, xv.y, au0[1]);
        au0[2] = fmaf(wu.x, xv.z, au0[2]); au0[3] = fmaf(wu.x, xv.w, au0[3]);
        au1[0] = fmaf(wu.y, xv.x, au1[0]); au1[1] = fmaf(wu.y, xv.y, au1[1]);
        au1[2] = fmaf(wu.y, xv.z, au1[2]); au1[3] = fmaf(wu.y, xv.w, au1[3]);
        av0[0] = fmaf(wv.x, tv.x, av0[0]); av0[1] = fmaf(wv.x, tv.y, av0[1]);
        av0[2] = fmaf(wv.x, tv.z, av0[2]); av0[3] = fmaf(wv.x, tv.w, av0[3]);
        av1[0] = fmaf(wv.y, tv.x, av1[0]); av1[1] = fmaf(wv.y, tv.y, av1[1]);
        av1[2] = fmaf(wv.y, tv.z, av1[2]); av1[3] = fmaf(wv.y, tv.w, av1[3]);
    }

    // ---- combine i-halves (lane ^ 32), then dot+bias, reduce over kq ----
    #pragma unroll
    for (int q = 0; q < 4; ++q) {
        au0[q] += __shfl_xor(au0[q], 32);
        au1[q] += __shfl_xor(au1[q], 32);
        av0[q] += __shfl_xor(av0[q], 32);
        av1[q] += __shfl_xor(av1[q], 32);
    }
    const int c0 = C0 + w, c1 = C0 + w + 8;
    const float br0 = b_row[c0], bc0 = b_col[c0];
    const float br1 = b_row[c1], bc1 = b_col[c1];

    float p0 = 0.f, p1 = 0.f;
    #pragma unroll
    for (int q = 0; q < 4; ++q) {
        p0 += (au0[q] + br0) * (av0[q] + bc0);
        p1 += (au1[q] + br1) * (av1[q] + bc1);
    }
    #pragma unroll
    for (int off = 1; off < 32; off <<= 1) {
        p0 += __shfl_xor(p0, off);
        p1 += __shfl_xor(p1, off);
    }
    if (lane == 0) { s_lds[w] = p0; s_lds[w + 8] = p1; }
    __syncthreads();

    // ---- write phase: this block's 16 slabs (1 MB), coalesced float4 ----
    float4* out4 = reinterpret_cast<float4*>(out);
    #pragma unroll
    for (int cl = 0; cl < 16; ++cl) {
        const float val = s_lds[cl];           // LDS broadcast
        float4 v4;
        v4.x = v4.y = v4.z = v4.w = val;
        float4* o = out4 + (size_t)(b * CDIM + C0 + cl) * 4096;
        #pragma unroll
        for (int r = 0; r < 8; ++r) {
            o[tid + 512 * r] = v4;
        }
    }
}

extern "C" void kernel_launch(void* const* d_in, const int* in_sizes, int n_in,
                              void* d_out, int out_size, void* d_ws, size_t ws_size,
                              hipStream_t stream) {
    const float* x     = (const float*)d_in[0];
    const float* w_col = (const float*)d_in[1];
    const float* b_col = (const float*)d_in[2];
    const float* w_row = (const float*)d_in[3];
    const float* b_row = (const float*)d_in[4];
    float* out = (float*)d_out;

    fused_kernel<<<256, 512, 0, stream>>>(x, w_col, b_col, w_row, b_row, out);
}